// Round 7
// baseline (360.864 us; speedup 1.0000x reference)
//
#include <hip/hip_runtime.h>
#include <hip/hip_bf16.h>
#include <cstdint>

// SelfAttention: B=8, S=2048, D_IN=D_OUT=768, fp32 in/out.
// R7 = R6 with the preprocess grid bug fixed (R6 launched 4.72M float4
// convert slots for 3.15M actual groups -> OOB read of x, crash; the count
// is MTOT*ND/4 = 3,145,728 = 4096 blocks x 256 thr x 3 iters).
// R6 changes under test: non-temporal epilogue stores (E/out/qkvb/vt are
// streamed once; keep them out of L2 so staging re-reads stay resident)
// + vectorized preprocess (float4 W-transpose, nt loads).
// fp8 REJECTED by error model calibrated on measured bf16 absmax 4.9e-4:
// E/V in e4m3 -> ~2.5e-3 absmax > 1.46e-3 threshold. bf16 is the floor.
// GEMM core: 128x128 tile, BK=64, XOR-swizzled LDS (0 conflicts), m97
// plateau ~800 TF (m99-m141: not movable from HIP source).
// ws: xb 25.2M | Wt 3.5M | qkvb(QK) 50.3M | vt 25.2M | probs(E) 67.1M | rowsum 64K

#define NB 8
#define NS 2048
#define ND 768
#define NQK 1536   // qkvb row width (Q|K only)
#define MTOT 16384 // NB*NS

using f32x4 = __attribute__((ext_vector_type(4))) float;
using s16x8 = __attribute__((ext_vector_type(8))) short;

struct alignas(16) bf16x8 { __hip_bfloat16 h[8]; };
struct alignas(8)  bf16x4 { __hip_bfloat16 h[4]; };

// ---------------- preprocess: convert x, transpose W, zero rowsum ----------------
// blocks [0, 4096): xb = bf16(x), 3 float4/thread (4096*256*3 = 3,145,728 = MTOT*ND/4)
// blocks [4096, 4096+1728): Wt[e][n][k] = bf16(W[e][k][n]), 32x32 tiles
// blocks [5824, 5840): rowsum = 0
#define CVT_BLOCKS 4096
#define WT_BLOCKS 1728
__global__ __launch_bounds__(256) void preprocess_kernel(const float* __restrict__ x,
                                                         __hip_bfloat16* __restrict__ xb,
                                                         const float* __restrict__ W,
                                                         __hip_bfloat16* __restrict__ Wt,
                                                         float* __restrict__ rowsum) {
    __shared__ float tile[32][33];
    const int tid = threadIdx.x;
    if (blockIdx.x < CVT_BLOCKS) {
#pragma unroll
        for (int it = 0; it < 3; ++it) {
            const int i = (it * CVT_BLOCKS + blockIdx.x) * 256 + tid;
            const f32x4 v = __builtin_nontemporal_load((const f32x4*)x + i);
            bf16x4 o;
            o.h[0] = __float2bfloat16(v[0]);
            o.h[1] = __float2bfloat16(v[1]);
            o.h[2] = __float2bfloat16(v[2]);
            o.h[3] = __float2bfloat16(v[3]);
            ((bf16x4*)xb)[i] = o;
        }
    } else if (blockIdx.x < CVT_BLOCKS + WT_BLOCKS) {
        const int bid = blockIdx.x - CVT_BLOCKS;       // 0..1727 = 3*24*24
        const int e = bid / 576, rem = bid % 576;
        const int k0 = (rem / 24) * 32, n0 = (rem % 24) * 32;
        const float* Wp = W + (size_t)e * ND * ND;
        __hip_bfloat16* Wo = Wt + (size_t)e * ND * ND;
        {   // load 32x32 via float4: ty=row (32), tx=float4-col (8)
            const int ty = tid >> 3, tx = tid & 7;
            const f32x4 v = __builtin_nontemporal_load(
                (const f32x4*)&Wp[(k0 + ty) * ND + n0 + tx * 4]);
#pragma unroll
            for (int q = 0; q < 4; ++q) tile[ty][tx * 4 + q] = v[q];
        }
        __syncthreads();
        {   // store transposed: np=out row (32), kq=k-quad (8)
            const int np = tid >> 3, kq = tid & 7;
            bf16x4 o;
#pragma unroll
            for (int q = 0; q < 4; ++q) o.h[q] = __float2bfloat16(tile[kq * 4 + q][np]);
            *(bf16x4*)&Wo[(long)(n0 + np) * ND + k0 + kq * 4] = o;
        }
    } else {
        const int i = (blockIdx.x - CVT_BLOCKS - WT_BLOCKS) * 1024 + tid * 4;
        f32x4 z = {0.f, 0.f, 0.f, 0.f};
        *(f32x4*)(rowsum + i) = z;
    }
}

// ---------------- MFMA GEMM: C[m][n] = epilogue( sum_k A[m][k]*B[n][k] ) ----------------
// 128x128 tile, BK=64, 4 waves, 4x4 16x16x32 MFMAs/wave, global_load_lds
// width=16 staging, XOR-swizzled LDS (0 bank conflicts, measured R2/R3).
// All epilogue stores NON-TEMPORAL (streamed once; protect L2 for staging).
// EPI 2: QKV split (tileN<1536 -> bf16 C; else transpose tile -> vt[b][d][s])
// EPI 3: scores    (store bf16 exp(scale*acc), atomicAdd fp32 row sums)
// EPI 4: PV        (f32 C scaled by 1/rowsum[row])
__device__ __forceinline__ void storeNT(float* p, float v) {
    __builtin_nontemporal_store(v, p);
}
__device__ __forceinline__ void storeNT(__hip_bfloat16* p, float v) {
    __hip_bfloat16 h = __float2bfloat16(v);
    __builtin_nontemporal_store(*(short*)&h, (short*)p);
}

template <typename OutT, int EPI, bool BATCH_X>
__global__ __launch_bounds__(256, 3) void gemm_bt_kernel(
    const __hip_bfloat16* __restrict__ A,   // [M][lda], k-contiguous
    const __hip_bfloat16* __restrict__ Bm,  // [N][ldb], k-contiguous
    OutT* __restrict__ C,                   // [M][ldc]
    __hip_bfloat16* __restrict__ vtOut,     // EPI==2
    float* __restrict__ rowsum,             // EPI==3 (accumulate) / EPI==4 (read)
    int K, int lda, int ldb, int ldc,
    long sA, long sB, long sC, float scale) {
    __shared__ char smem[32768];
    char* AsB = smem;
    char* BsB = smem + 16384;

    int b, tileM, tileN;
    if (BATCH_X) {  // batch on x => batch == linear%8 == XCD id (L2 locality)
        b = blockIdx.x; tileN = blockIdx.y * 128; tileM = blockIdx.z * 128;
    } else {
        b = blockIdx.z; tileN = blockIdx.x * 128; tileM = blockIdx.y * 128;
    }
    A  += (long)b * sA;
    Bm += (long)b * sB;
    C  += (long)b * sC;

    const int tid  = threadIdx.x;
    const int lane = tid & 63;
    const int wave = tid >> 6;
    const int wm = (wave >> 1) * 64;
    const int wn = (wave & 1) * 64;
    const int quad = lane >> 4;
    const int lrow = lane & 15;

    // staging: thread covers 16B; row = tid>>3 (0..31), swizzled col chunk
    const int srow = tid >> 3;
    const int scol = ((tid & 7) ^ (srow & 7)) << 3;

    f32x4 acc[4][4];
    const f32x4 zero = {0.f, 0.f, 0.f, 0.f};
#pragma unroll
    for (int i = 0; i < 4; ++i)
#pragma unroll
        for (int j = 0; j < 4; ++j) acc[i][j] = zero;

    const __hip_bfloat16* gA = A + (long)(tileM + srow) * lda + scol;
    const __hip_bfloat16* gB = Bm + (long)(tileN + srow) * ldb + scol;
    const int ldsOff = tid * 16;  // bytes; dest = wave-uniform base + lane*16

    typedef const __attribute__((address_space(1))) void* gp;
    typedef __attribute__((address_space(3))) void* sp;

    const int swa = (lrow & 7) << 4;  // XOR byte swizzle for fragment reads

    for (int k0 = 0; k0 < K; k0 += 64) {
        __syncthreads();
#pragma unroll
        for (int j = 0; j < 4; ++j)
            __builtin_amdgcn_global_load_lds((gp)(gA + (long)(j * 32) * lda + k0),
                                             (sp)(AsB + j * 4096 + ldsOff), 16, 0, 0);
#pragma unroll
        for (int j = 0; j < 4; ++j)
            __builtin_amdgcn_global_load_lds((gp)(gB + (long)(j * 32) * ldb + k0),
                                             (sp)(BsB + j * 4096 + ldsOff), 16, 0, 0);
        __syncthreads();

#pragma unroll
        for (int kk = 0; kk < 2; ++kk) {
            s16x8 af[4], bfr[4];
#pragma unroll
            for (int i = 0; i < 4; ++i)
                af[i] = *(const s16x8*)(AsB + (wm + i * 16 + lrow) * 128 +
                                        ((((kk << 2) | quad) << 4) ^ swa));
#pragma unroll
            for (int j = 0; j < 4; ++j)
                bfr[j] = *(const s16x8*)(BsB + (wn + j * 16 + lrow) * 128 +
                                         ((((kk << 2) | quad) << 4) ^ swa));
#pragma unroll
            for (int i = 0; i < 4; ++i)
#pragma unroll
                for (int j = 0; j < 4; ++j)
                    acc[i][j] = __builtin_amdgcn_mfma_f32_16x16x32_bf16(af[i], bfr[j], acc[i][j], 0, 0, 0);
        }
    }

    // ---------------- epilogues (all stores non-temporal) ----------------
    if (EPI == 2 && tileN >= NQK) {
        // V tile: transpose through LDS, store to vt[b'][d][s].
        __syncthreads();
        char* T = smem;  // 32KB scratch
#pragma unroll
        for (int i = 0; i < 4; ++i) {
#pragma unroll
            for (int j = 0; j < 4; ++j) {
                const int d = wn + j * 16 + lrow;       // local col (V feature)
                const int s = wm + i * 16 + quad * 4;   // granule of 4 rows
                bf16x4 g;
#pragma unroll
                for (int r = 0; r < 4; ++r) g.h[r] = __float2bfloat16(acc[i][j][r]);
                const int c = s >> 3;
                const int off = d * 256 + (((c ^ (d & 15)) << 4) | ((s & 4) << 1));
                *(bf16x4*)(T + off) = g;
            }
        }
        __syncthreads();
        const int dl = tid >> 1, half = tid & 1;
        const long bb = tileM >> 11;
        const int s0 = tileM & (NS - 1);
        const long dg = (long)(tileN - NQK) + dl;
        __hip_bfloat16* dst = vtOut + (bb * ND + dg) * NS + s0;
#pragma unroll
        for (int cc = 0; cc < 8; ++cc) {
            const int c2 = half * 8 + cc;
            s16x8 val = *(const s16x8*)(T + dl * 256 + ((c2 ^ (dl & 15)) << 4));
            __builtin_nontemporal_store(val, (s16x8*)(dst + c2 * 8));
        }
        return;
    }

    if (EPI == 3) {
        // scores: store unnormalized E = exp(scale*acc) bf16; row-sum atomics.
        // Sum uses the bf16-ROUNDED values so normalization matches PV's input.
#pragma unroll
        for (int i = 0; i < 4; ++i) {
            float rs[4] = {0.f, 0.f, 0.f, 0.f};
#pragma unroll
            for (int j = 0; j < 4; ++j) {
                const int col = tileN + wn + j * 16 + lrow;
#pragma unroll
                for (int r = 0; r < 4; ++r) {
                    const int row = tileM + wm + i * 16 + quad * 4 + r;
                    const float e = __expf(acc[i][j][r] * scale);  // |logit|<~2.5: safe
                    const __hip_bfloat16 h = __float2bfloat16(e);
                    __builtin_nontemporal_store(*(const short*)&h,
                                                (short*)(C + (long)row * ldc + col));
                    rs[r] += __bfloat162float(h);
                }
            }
#pragma unroll
            for (int r = 0; r < 4; ++r) {
#pragma unroll
                for (int off = 1; off < 16; off <<= 1) rs[r] += __shfl_xor(rs[r], off);
            }
            if (lrow == 0) {
#pragma unroll
                for (int r = 0; r < 4; ++r)
                    atomicAdd(rowsum + (long)b * NS + tileM + wm + i * 16 + quad * 4 + r, rs[r]);
            }
        }
        return;
    }

    if (EPI == 4) {
        // PV: normalize by row sum.
#pragma unroll
        for (int i = 0; i < 4; ++i) {
            float inv[4];
#pragma unroll
            for (int r = 0; r < 4; ++r)
                inv[r] = 1.0f / rowsum[(long)b * NS + tileM + wm + i * 16 + quad * 4 + r];
#pragma unroll
            for (int j = 0; j < 4; ++j) {
                const int col = tileN + wn + j * 16 + lrow;
#pragma unroll
                for (int r = 0; r < 4; ++r) {
                    const int row = tileM + wm + i * 16 + quad * 4 + r;
                    storeNT(C + (long)row * ldc + col, acc[i][j][r] * inv[r]);
                }
            }
        }
        return;
    }

    // EPI==2 Q|K path: plain bf16 store
#pragma unroll
    for (int i = 0; i < 4; ++i) {
#pragma unroll
        for (int j = 0; j < 4; ++j) {
            const int col = tileN + wn + j * 16 + lrow;
#pragma unroll
            for (int r = 0; r < 4; ++r) {
                const int row = tileM + wm + i * 16 + quad * 4 + r;
                storeNT(C + (long)row * ldc + col, acc[i][j][r] * scale);
            }
        }
    }
}

// ---------------- launch ----------------
extern "C" void kernel_launch(void* const* d_in, const int* in_sizes, int n_in,
                              void* d_out, int out_size, void* d_ws, size_t ws_size,
                              hipStream_t stream) {
    const float* x   = (const float*)d_in[0];  // [8][2048][768]
    const float* QKV = (const float*)d_in[1];  // [3][768][768]
    float* out = (float*)d_out;                // [8][2048][768]

    uint8_t* ws = (uint8_t*)d_ws;
    constexpr size_t XB_BYTES  = (size_t)MTOT * ND * 2;     // 25.2M
    constexpr size_t WT_BYTES  = (size_t)3 * ND * ND * 2;   //  3.5M
    constexpr size_t QKV_BYTES = (size_t)MTOT * NQK * 2;    // 50.3M (Q|K only)
    constexpr size_t VT_BYTES  = (size_t)NB * ND * NS * 2;  // 25.2M
    constexpr size_t PR_BYTES  = (size_t)MTOT * NS * 2;     // 67.1M
    __hip_bfloat16* xb    = (__hip_bfloat16*)(ws);
    __hip_bfloat16* Wt    = (__hip_bfloat16*)(ws + XB_BYTES);
    __hip_bfloat16* qkvb  = (__hip_bfloat16*)(ws + XB_BYTES + WT_BYTES);
    __hip_bfloat16* vt    = (__hip_bfloat16*)(ws + XB_BYTES + WT_BYTES + QKV_BYTES);
    __hip_bfloat16* probs = (__hip_bfloat16*)(ws + XB_BYTES + WT_BYTES + QKV_BYTES + VT_BYTES);
    float*          rowsum= (float*)(ws + XB_BYTES + WT_BYTES + QKV_BYTES + VT_BYTES + PR_BYTES);

    const float scale = 0.03608439182435161f;  // 1/sqrt(768)

    // 1. preprocess: xb = bf16(x); Wt = bf16(W^T); rowsum = 0
    preprocess_kernel<<<CVT_BLOCKS + WT_BLOCKS + 16, 256, 0, stream>>>(x, xb, QKV, Wt, rowsum);
    // 2. fused QKV projection: Q|K -> qkvb [16384][1536]; V -> vt[b][d][s]
    gemm_bt_kernel<__hip_bfloat16, 2, false><<<dim3(2304 / 128, MTOT / 128, 1), 256, 0, stream>>>(
        xb, Wt, qkvb, vt, nullptr, ND, ND, ND, NQK, 0, 0, 0, 1.0f);
    // 3. E = exp(scale * Q K^T), rowsum += (per batch; batch on x for XCD-L2 locality)
    gemm_bt_kernel<__hip_bfloat16, 3, true><<<dim3(NB, NS / 128, NS / 128), 256, 0, stream>>>(
        qkvb, qkvb + ND, probs, nullptr, rowsum, ND, NQK, NQK, NS,
        (long)NS * NQK, (long)NS * NQK, (long)NS * NS, scale);
    // 4. out = (E @ V) / rowsum  (fp32 out)
    gemm_bt_kernel<float, 4, true><<<dim3(NB, ND / 128, NS / 128), 256, 0, stream>>>(
        probs, vt, out, nullptr, rowsum, NS, NS, NS, ND,
        (long)NS * NS, (long)ND * NS, (long)NS * ND, 1.0f);
}

// Round 8
// 280.096 us; speedup vs baseline: 1.2884x; 1.2884x over previous
//
#include <hip/hip_runtime.h>
#include <hip/hip_bf16.h>
#include <cstdint>

// SelfAttention: B=8, S=2048, D_IN=D_OUT=768, fp32 in/out.
// R8 = R5 epilogues (PLAIN stores) + R7's fixed vectorized preprocess.
// R7 post-mortem: __builtin_nontemporal_store on 2B/4B epilogue elements
// defeats L2 write-coalescing -> partial-line RMW writebacks, WRITE_SIZE
// 74->197MB, scores GEMM 76->114us. Measured, reverted. nt LOADS kept
// (single-use inputs, harmless).
// Structure: 4 kernels — preprocess (x->bf16, Wt=bf16(W^T), rowsum=0),
// QKV GEMM (Q|K -> qkvb, V -> vt via epilogue transpose), scores GEMM
// (E=exp(scale*QK^T) bf16 + fp32 rowsum atomics), PV GEMM (out=(E@V)/rowsum).
// GEMM core: 128x128 tile, BK=64, XOR-swizzled LDS (0 bank conflicts),
// global_load_lds width=16; ~34% MfmaUtil = m97 plateau (m99-m141: not
// movable from HIP source). fp8 rejected: error model vs 1.46e-3 threshold.
// ws: xb 25.2M | Wt 3.5M | qkvb(QK) 50.3M | vt 25.2M | probs(E) 67.1M | rowsum 64K

#define NB 8
#define NS 2048
#define ND 768
#define NQK 1536   // qkvb row width (Q|K only)
#define MTOT 16384 // NB*NS

using f32x4 = __attribute__((ext_vector_type(4))) float;
using s16x8 = __attribute__((ext_vector_type(8))) short;

struct alignas(16) bf16x8 { __hip_bfloat16 h[8]; };
struct alignas(8)  bf16x4 { __hip_bfloat16 h[4]; };

// ---------------- preprocess: convert x, transpose W, zero rowsum ----------------
// blocks [0, 4096): xb = bf16(x), 3 float4/thread (4096*256*3 = 3,145,728 = MTOT*ND/4)
// blocks [4096, 4096+1728): Wt[e][n][k] = bf16(W[e][k][n]), 32x32 tiles
// blocks [5824, 5840): rowsum = 0
#define CVT_BLOCKS 4096
#define WT_BLOCKS 1728
__global__ __launch_bounds__(256) void preprocess_kernel(const float* __restrict__ x,
                                                         __hip_bfloat16* __restrict__ xb,
                                                         const float* __restrict__ W,
                                                         __hip_bfloat16* __restrict__ Wt,
                                                         float* __restrict__ rowsum) {
    __shared__ float tile[32][33];
    const int tid = threadIdx.x;
    if (blockIdx.x < CVT_BLOCKS) {
#pragma unroll
        for (int it = 0; it < 3; ++it) {
            const int i = (it * CVT_BLOCKS + blockIdx.x) * 256 + tid;
            const f32x4 v = __builtin_nontemporal_load((const f32x4*)x + i);
            bf16x4 o;
            o.h[0] = __float2bfloat16(v[0]);
            o.h[1] = __float2bfloat16(v[1]);
            o.h[2] = __float2bfloat16(v[2]);
            o.h[3] = __float2bfloat16(v[3]);
            ((bf16x4*)xb)[i] = o;
        }
    } else if (blockIdx.x < CVT_BLOCKS + WT_BLOCKS) {
        const int bid = blockIdx.x - CVT_BLOCKS;       // 0..1727 = 3*24*24
        const int e = bid / 576, rem = bid % 576;
        const int k0 = (rem / 24) * 32, n0 = (rem % 24) * 32;
        const float* Wp = W + (size_t)e * ND * ND;
        __hip_bfloat16* Wo = Wt + (size_t)e * ND * ND;
        {   // load 32x32 via float4: ty=row (32), tx=float4-col (8)
            const int ty = tid >> 3, tx = tid & 7;
            const f32x4 v = __builtin_nontemporal_load(
                (const f32x4*)&Wp[(k0 + ty) * ND + n0 + tx * 4]);
#pragma unroll
            for (int q = 0; q < 4; ++q) tile[ty][tx * 4 + q] = v[q];
        }
        __syncthreads();
        {   // store transposed: np=out row (32), kq=k-quad (8)
            const int np = tid >> 3, kq = tid & 7;
            bf16x4 o;
#pragma unroll
            for (int q = 0; q < 4; ++q) o.h[q] = __float2bfloat16(tile[kq * 4 + q][np]);
            *(bf16x4*)&Wo[(long)(n0 + np) * ND + k0 + kq * 4] = o;
        }
    } else {
        const int i = (blockIdx.x - CVT_BLOCKS - WT_BLOCKS) * 1024 + tid * 4;
        f32x4 z = {0.f, 0.f, 0.f, 0.f};
        *(f32x4*)(rowsum + i) = z;
    }
}

// ---------------- MFMA GEMM: C[m][n] = epilogue( sum_k A[m][k]*B[n][k] ) ----------------
// 128x128 tile, BK=64, 4 waves, 4x4 16x16x32 MFMAs/wave, global_load_lds
// width=16 staging, XOR-swizzled LDS (0 bank conflicts, measured R2/R3).
// EPI 2: QKV split (tileN<1536 -> bf16 C; else transpose tile -> vt[b][d][s])
// EPI 3: scores    (store bf16 exp(scale*acc), atomicAdd fp32 row sums)
// EPI 4: PV        (f32 C scaled by 1/rowsum[row])
__device__ __forceinline__ void storeC(float* p, float v) { *p = v; }
__device__ __forceinline__ void storeC(__hip_bfloat16* p, float v) { *p = __float2bfloat16(v); }

template <typename OutT, int EPI, bool BATCH_X>
__global__ __launch_bounds__(256, 3) void gemm_bt_kernel(
    const __hip_bfloat16* __restrict__ A,   // [M][lda], k-contiguous
    const __hip_bfloat16* __restrict__ Bm,  // [N][ldb], k-contiguous
    OutT* __restrict__ C,                   // [M][ldc]
    __hip_bfloat16* __restrict__ vtOut,     // EPI==2
    float* __restrict__ rowsum,             // EPI==3 (accumulate) / EPI==4 (read)
    int K, int lda, int ldb, int ldc,
    long sA, long sB, long sC, float scale) {
    __shared__ char smem[32768];
    char* AsB = smem;
    char* BsB = smem + 16384;

    int b, tileM, tileN;
    if (BATCH_X) {  // batch on x => batch == linear%8 == XCD id (L2 locality)
        b = blockIdx.x; tileN = blockIdx.y * 128; tileM = blockIdx.z * 128;
    } else {
        b = blockIdx.z; tileN = blockIdx.x * 128; tileM = blockIdx.y * 128;
    }
    A  += (long)b * sA;
    Bm += (long)b * sB;
    C  += (long)b * sC;

    const int tid  = threadIdx.x;
    const int lane = tid & 63;
    const int wave = tid >> 6;
    const int wm = (wave >> 1) * 64;
    const int wn = (wave & 1) * 64;
    const int quad = lane >> 4;
    const int lrow = lane & 15;

    // staging: thread covers 16B; row = tid>>3 (0..31), swizzled col chunk
    const int srow = tid >> 3;
    const int scol = ((tid & 7) ^ (srow & 7)) << 3;

    f32x4 acc[4][4];
    const f32x4 zero = {0.f, 0.f, 0.f, 0.f};
#pragma unroll
    for (int i = 0; i < 4; ++i)
#pragma unroll
        for (int j = 0; j < 4; ++j) acc[i][j] = zero;

    const __hip_bfloat16* gA = A + (long)(tileM + srow) * lda + scol;
    const __hip_bfloat16* gB = Bm + (long)(tileN + srow) * ldb + scol;
    const int ldsOff = tid * 16;  // bytes; dest = wave-uniform base + lane*16

    typedef const __attribute__((address_space(1))) void* gp;
    typedef __attribute__((address_space(3))) void* sp;

    const int swa = (lrow & 7) << 4;  // XOR byte swizzle for fragment reads

    for (int k0 = 0; k0 < K; k0 += 64) {
        __syncthreads();
#pragma unroll
        for (int j = 0; j < 4; ++j)
            __builtin_amdgcn_global_load_lds((gp)(gA + (long)(j * 32) * lda + k0),
                                             (sp)(AsB + j * 4096 + ldsOff), 16, 0, 0);
#pragma unroll
        for (int j = 0; j < 4; ++j)
            __builtin_amdgcn_global_load_lds((gp)(gB + (long)(j * 32) * ldb + k0),
                                             (sp)(BsB + j * 4096 + ldsOff), 16, 0, 0);
        __syncthreads();

#pragma unroll
        for (int kk = 0; kk < 2; ++kk) {
            s16x8 af[4], bfr[4];
#pragma unroll
            for (int i = 0; i < 4; ++i)
                af[i] = *(const s16x8*)(AsB + (wm + i * 16 + lrow) * 128 +
                                        ((((kk << 2) | quad) << 4) ^ swa));
#pragma unroll
            for (int j = 0; j < 4; ++j)
                bfr[j] = *(const s16x8*)(BsB + (wn + j * 16 + lrow) * 128 +
                                         ((((kk << 2) | quad) << 4) ^ swa));
#pragma unroll
            for (int i = 0; i < 4; ++i)
#pragma unroll
                for (int j = 0; j < 4; ++j)
                    acc[i][j] = __builtin_amdgcn_mfma_f32_16x16x32_bf16(af[i], bfr[j], acc[i][j], 0, 0, 0);
        }
    }

    // ---------------- epilogues ----------------
    if (EPI == 2 && tileN >= NQK) {
        // V tile: transpose through LDS, store to vt[b'][d][s].
        __syncthreads();
        char* T = smem;  // 32KB scratch
#pragma unroll
        for (int i = 0; i < 4; ++i) {
#pragma unroll
            for (int j = 0; j < 4; ++j) {
                const int d = wn + j * 16 + lrow;       // local col (V feature)
                const int s = wm + i * 16 + quad * 4;   // granule of 4 rows
                bf16x4 g;
#pragma unroll
                for (int r = 0; r < 4; ++r) g.h[r] = __float2bfloat16(acc[i][j][r]);
                const int c = s >> 3;
                const int off = d * 256 + (((c ^ (d & 15)) << 4) | ((s & 4) << 1));
                *(bf16x4*)(T + off) = g;
            }
        }
        __syncthreads();
        const int dl = tid >> 1, half = tid & 1;
        const long bb = tileM >> 11;
        const int s0 = tileM & (NS - 1);
        const long dg = (long)(tileN - NQK) + dl;
        __hip_bfloat16* dst = vtOut + (bb * ND + dg) * NS + s0;
#pragma unroll
        for (int cc = 0; cc < 8; ++cc) {
            const int c2 = half * 8 + cc;
            s16x8 val = *(const s16x8*)(T + dl * 256 + ((c2 ^ (dl & 15)) << 4));
            *(s16x8*)(dst + c2 * 8) = val;
        }
        return;
    }

    if (EPI == 3) {
        // scores: store unnormalized E = exp(scale*acc) bf16; row-sum atomics.
        // Sum uses the bf16-ROUNDED values so normalization matches PV's input.
#pragma unroll
        for (int i = 0; i < 4; ++i) {
            float rs[4] = {0.f, 0.f, 0.f, 0.f};
#pragma unroll
            for (int j = 0; j < 4; ++j) {
                const int col = tileN + wn + j * 16 + lrow;
#pragma unroll
                for (int r = 0; r < 4; ++r) {
                    const int row = tileM + wm + i * 16 + quad * 4 + r;
                    const float e = __expf(acc[i][j][r] * scale);  // |logit|<~2.5: safe
                    const __hip_bfloat16 h = __float2bfloat16(e);
                    storeC(C + (long)row * ldc + col, __bfloat162float(h));
                    rs[r] += __bfloat162float(h);
                }
            }
#pragma unroll
            for (int r = 0; r < 4; ++r) {
#pragma unroll
                for (int off = 1; off < 16; off <<= 1) rs[r] += __shfl_xor(rs[r], off);
            }
            if (lrow == 0) {
#pragma unroll
                for (int r = 0; r < 4; ++r)
                    atomicAdd(rowsum + (long)b * NS + tileM + wm + i * 16 + quad * 4 + r, rs[r]);
            }
        }
        return;
    }

    if (EPI == 4) {
        // PV: normalize by row sum.
#pragma unroll
        for (int i = 0; i < 4; ++i) {
            float inv[4];
#pragma unroll
            for (int r = 0; r < 4; ++r)
                inv[r] = 1.0f / rowsum[(long)b * NS + tileM + wm + i * 16 + quad * 4 + r];
#pragma unroll
            for (int j = 0; j < 4; ++j) {
                const int col = tileN + wn + j * 16 + lrow;
#pragma unroll
                for (int r = 0; r < 4; ++r) {
                    const int row = tileM + wm + i * 16 + quad * 4 + r;
                    storeC(C + (long)row * ldc + col, acc[i][j][r] * inv[r]);
                }
            }
        }
        return;
    }

    // EPI==2 Q|K path: plain bf16 store
#pragma unroll
    for (int i = 0; i < 4; ++i) {
#pragma unroll
        for (int j = 0; j < 4; ++j) {
            const int col = tileN + wn + j * 16 + lrow;
#pragma unroll
            for (int r = 0; r < 4; ++r) {
                const int row = tileM + wm + i * 16 + quad * 4 + r;
                storeC(C + (long)row * ldc + col, acc[i][j][r] * scale);
            }
        }
    }
}

// ---------------- launch ----------------
extern "C" void kernel_launch(void* const* d_in, const int* in_sizes, int n_in,
                              void* d_out, int out_size, void* d_ws, size_t ws_size,
                              hipStream_t stream) {
    const float* x   = (const float*)d_in[0];  // [8][2048][768]
    const float* QKV = (const float*)d_in[1];  // [3][768][768]
    float* out = (float*)d_out;                // [8][2048][768]

    uint8_t* ws = (uint8_t*)d_ws;
    constexpr size_t XB_BYTES  = (size_t)MTOT * ND * 2;     // 25.2M
    constexpr size_t WT_BYTES  = (size_t)3 * ND * ND * 2;   //  3.5M
    constexpr size_t QKV_BYTES = (size_t)MTOT * NQK * 2;    // 50.3M (Q|K only)
    constexpr size_t VT_BYTES  = (size_t)NB * ND * NS * 2;  // 25.2M
    constexpr size_t PR_BYTES  = (size_t)MTOT * NS * 2;     // 67.1M
    __hip_bfloat16* xb    = (__hip_bfloat16*)(ws);
    __hip_bfloat16* Wt    = (__hip_bfloat16*)(ws + XB_BYTES);
    __hip_bfloat16* qkvb  = (__hip_bfloat16*)(ws + XB_BYTES + WT_BYTES);
    __hip_bfloat16* vt    = (__hip_bfloat16*)(ws + XB_BYTES + WT_BYTES + QKV_BYTES);
    __hip_bfloat16* probs = (__hip_bfloat16*)(ws + XB_BYTES + WT_BYTES + QKV_BYTES + VT_BYTES);
    float*          rowsum= (float*)(ws + XB_BYTES + WT_BYTES + QKV_BYTES + VT_BYTES + PR_BYTES);

    const float scale = 0.03608439182435161f;  // 1/sqrt(768)

    // 1. preprocess: xb = bf16(x); Wt = bf16(W^T); rowsum = 0
    preprocess_kernel<<<CVT_BLOCKS + WT_BLOCKS + 16, 256, 0, stream>>>(x, xb, QKV, Wt, rowsum);
    // 2. fused QKV projection: Q|K -> qkvb [16384][1536]; V -> vt[b][d][s]
    gemm_bt_kernel<__hip_bfloat16, 2, false><<<dim3(2304 / 128, MTOT / 128, 1), 256, 0, stream>>>(
        xb, Wt, qkvb, vt, nullptr, ND, ND, ND, NQK, 0, 0, 0, 1.0f);
    // 3. E = exp(scale * Q K^T), rowsum += (per batch; batch on x for XCD-L2 locality)
    gemm_bt_kernel<__hip_bfloat16, 3, true><<<dim3(NB, NS / 128, NS / 128), 256, 0, stream>>>(
        qkvb, qkvb + ND, probs, nullptr, rowsum, ND, NQK, NQK, NS,
        (long)NS * NQK, (long)NS * NQK, (long)NS * NS, scale);
    // 4. out = (E @ V) / rowsum  (fp32 out)
    gemm_bt_kernel<float, 4, true><<<dim3(NB, ND / 128, NS / 128), 256, 0, stream>>>(
        probs, vt, out, nullptr, rowsum, NS, NS, NS, ND,
        (long)NS * NS, (long)ND * NS, (long)NS * ND, 1.0f);
}